// Round 1
// 1641.154 us; speedup vs baseline: 2.3657x; 2.3657x over previous
//
#include <hip/hip_runtime.h>
#include <hip/hip_bf16.h>
#include <math.h>

typedef __hip_bfloat16 bf16;
typedef unsigned short u16t;
typedef __bf16 bfx8 __attribute__((ext_vector_type(8)));
typedef float fx4 __attribute__((ext_vector_type(4)));
typedef unsigned short usx8 __attribute__((ext_vector_type(8)));

constexpr int Bq = 8, Hh = 64, Ww = 64, Nn = 4096, Cc = 384, NH = 8, CH = 1536;
constexpr int Mrows = Bq * Nn;  // 32768
constexpr int NS = 4;           // gram split-K factor
constexpr float EPSC = 1e-5f;
constexpr float SCALE = 0.14433756729740643f;  // 48^-0.5

__device__ __forceinline__ float toF(bf16 v) { return __bfloat162float(v); }

__device__ __forceinline__ float ldFlag(const void* p, size_t i, int f) {
    if (f) return __bfloat162float(((const bf16*)p)[i]);
    return ((const float*)p)[i];
}

__device__ __forceinline__ float u2f(u16t u) {
    unsigned int x = ((unsigned int)u) << 16;
    float fv;
    __builtin_memcpy(&fv, &x, 4);
    return fv;
}
__device__ __forceinline__ u16t f2u(float v) {
    bf16 h = __float2bfloat16(v);
    u16t u;
    __builtin_memcpy(&u, &h, 2);
    return u;
}
__device__ __forceinline__ fx4 mfma16(usx8 a, usx8 b, fx4 c) {
    return __builtin_amdgcn_mfma_f32_16x16x32_bf16(
        __builtin_bit_cast(bfx8, a), __builtin_bit_cast(bfx8, b), c, 0, 0, 0);
}

// ---- probe: bf16 N(0,1) data never has exponent>=134 (|v|>=128); fp32 halves do. ----
__global__ __launch_bounds__(256) void probe_k(const void* __restrict__ p, int* __restrict__ flag) {
    int t = threadIdx.x;
    int bad = 0;
    for (int i = t; i < 4096; i += 256) {
        unsigned short u = ((const unsigned short*)p)[i];
        unsigned e = (u >> 7) & 0xFF;
        if (e >= 134) bad++;
    }
    __shared__ int sh[256];
    sh[t] = bad;
    __syncthreads();
    for (int s = 128; s > 0; s >>= 1) {
        if (t < s) sh[t] += sh[t + s];
        __syncthreads();
    }
    if (t == 0) flag[0] = (sh[0] < 64) ? 1 : 0;  // 1 = bf16, 0 = fp32
}

// ---------------- depthwise 3x3 conv + bias + residual (channel-last) ----------------
template <int INM, typename OutT>
__global__ __launch_bounds__(384) void dwconv_cpe(const void* __restrict__ xin,
                                                  const void* __restrict__ w,
                                                  const void* __restrict__ bias,
                                                  OutT* __restrict__ out,
                                                  const int* __restrict__ flagp) {
    int f = *flagp;
    int bid = blockIdx.x;
    int c = threadIdx.x;  // 0..383
    int b = bid >> 12;
    int n = bid & 4095;
    int hh = n >> 6, ww2 = n & 63;
    size_t base = (size_t)b * Nn * Cc;
    float wreg[9];
#pragma unroll
    for (int j = 0; j < 9; j++) wreg[j] = ldFlag(w, c * 9 + j, f);
    float acc = ldFlag(bias, c, f);
#pragma unroll
    for (int ky = 0; ky < 3; ky++) {
        int yy = hh + ky - 1;
        if (yy < 0 || yy >= Hh) continue;
#pragma unroll
        for (int kx = 0; kx < 3; kx++) {
            int xx = ww2 + kx - 1;
            if (xx < 0 || xx >= Ww) continue;
            size_t idx = base + (size_t)(yy * Ww + xx) * Cc + c;
            float v = (INM == 1) ? toF(((const bf16*)xin)[idx]) : ldFlag(xin, idx, f);
            acc += v * wreg[ky * 3 + kx];
        }
    }
    size_t ci = base + (size_t)n * Cc + c;
    float xv = (INM == 1) ? toF(((const bf16*)xin)[ci]) : ldFlag(xin, ci, f);
    float r = xv + acc;
    size_t oi = (size_t)bid * Cc + c;
    if (sizeof(OutT) == 2) ((bf16*)out)[oi] = __float2bfloat16(r);
    else ((float*)out)[oi] = r;
}

// ---------------- per-row LN stats over C=384 ----------------
template <typename T>
__global__ __launch_bounds__(128) void rowstats_k(const T* __restrict__ in,
                                                  float* __restrict__ mu,
                                                  float* __restrict__ rs) {
    int r = blockIdx.x;
    int t = threadIdx.x;
    const T* row = in + (size_t)r * Cc;
    float v0, v1, v2;
    if (sizeof(T) == 2) {
        v0 = toF(((const bf16*)row)[t]);
        v1 = toF(((const bf16*)row)[t + 128]);
        v2 = toF(((const bf16*)row)[t + 256]);
    } else {
        v0 = ((const float*)row)[t];
        v1 = ((const float*)row)[t + 128];
        v2 = ((const float*)row)[t + 256];
    }
    float s = v0 + v1 + v2;
    float s2 = v0 * v0 + v1 * v1 + v2 * v2;
#pragma unroll
    for (int off = 32; off > 0; off >>= 1) {
        s += __shfl_down(s, off, 64);
        s2 += __shfl_down(s2, off, 64);
    }
    __shared__ float sh[4];
    int wv = t >> 6, ln = t & 63;
    if (ln == 0) { sh[wv] = s; sh[wv + 2] = s2; }
    __syncthreads();
    if (t == 0) {
        float S = sh[0] + sh[1], S2 = sh[2] + sh[3];
        float m = S * (1.0f / Cc);
        float var = S2 * (1.0f / Cc) - m * m;
        mu[r] = m;
        rs[r] = rsqrtf(var + EPSC);
    }
}

// ------- scalar tiled GEMM (kept for the small fp32 P = Gsum @ Wv step) -------
template <int AM, int OM, int WM, bool GELU, bool LNA, int RES, int AR>
__global__ __launch_bounds__(256) void gemm_k(const void* __restrict__ A, size_t aBatch,
                                              const void* __restrict__ W, size_t wBatch,
                                              int ldw, int colOff,
                                              const void* __restrict__ bias,
                                              const bf16* __restrict__ resid, size_t rBatch,
                                              const float* __restrict__ mu,
                                              const float* __restrict__ rs, size_t sBatch,
                                              const void* __restrict__ cg,
                                              const void* __restrict__ cb,
                                              void* __restrict__ out, size_t oBatch,
                                              size_t outRow0,
                                              int M, int K, int Nc,
                                              const int* __restrict__ flagp) {
    int f = *flagp;
    int z = blockIdx.z;
    const size_t MK = (size_t)M * K;
    __shared__ float As[16][68];
    __shared__ float Bs[16][68];
    int t = threadIdx.x;
    int tx = t & 15, ty = t >> 4;
    int row0 = blockIdx.x * 64, n0 = blockIdx.y * 64;
    float acc[4][4] = {};
    for (int k0 = 0; k0 < K; k0 += 16) {
#pragma unroll
        for (int i = 0; i < 4; i++) {
            int lin = i * 256 + t;
            int kk = lin & 15, m = lin >> 4;
            size_t ai = (size_t)z * aBatch + (size_t)(row0 + m) * K + k0 + kk;
            float v;
            if (AR > 1) {
                v = 0;
#pragma unroll
                for (int s = 0; s < AR; s++) v += ((const float*)A)[ai + (size_t)s * MK];
            } else {
                v = (AM == 0) ? ((const float*)A)[ai] : toF(((const bf16*)A)[ai]);
            }
            if (LNA) {
                float muv = mu[z * sBatch + row0 + m], rsv = rs[z * sBatch + row0 + m];
                v = (v - muv) * rsv * ldFlag(cg, k0 + kk, f) + ldFlag(cb, k0 + kk, f);
            }
            As[kk][m] = v;
        }
#pragma unroll
        for (int i = 0; i < 4; i++) {
            int lin = i * 256 + t;
            int nn2 = lin & 63, kk = lin >> 6;
            size_t wi = (size_t)z * wBatch + (size_t)(k0 + kk) * ldw + colOff + n0 + nn2;
            Bs[kk][nn2] = (WM == 1) ? toF(((const bf16*)W)[wi]) : ldFlag(W, wi, f);
        }
        __syncthreads();
#pragma unroll
        for (int kk = 0; kk < 16; kk++) {
            float a[4], bv[4];
#pragma unroll
            for (int i = 0; i < 4; i++) a[i] = As[kk][ty * 4 + i];
#pragma unroll
            for (int j = 0; j < 4; j++) bv[j] = Bs[kk][tx * 4 + j];
#pragma unroll
            for (int i = 0; i < 4; i++)
#pragma unroll
                for (int j = 0; j < 4; j++) acc[i][j] += a[i] * bv[j];
        }
        __syncthreads();
    }
#pragma unroll
    for (int i = 0; i < 4; i++) {
        int m = row0 + ty * 4 + i;
#pragma unroll
        for (int j = 0; j < 4; j++) {
            int nn2 = n0 + tx * 4 + j;
            float v = acc[i][j];
            if (bias) v += ldFlag(bias, nn2, f);
            if (GELU) v = 0.5f * v * (1.0f + erff(v * 0.70710678118654752f));
            if (RES == 1) v += toF(resid[(size_t)z * rBatch + (size_t)m * Nc + nn2]);
            if (RES == 2) {
                size_t ai = (size_t)z * aBatch + (size_t)m * K + nn2;
                float a = (AM == 0) ? ((const float*)A)[ai] : toF(((const bf16*)A)[ai]);
                float muv = mu[z * sBatch + m], rsv = rs[z * sBatch + m];
                v += (a - muv) * rsv * ldFlag(cg, nn2, f) + ldFlag(cb, nn2, f);
            }
            size_t oi = (size_t)z * oBatch + (outRow0 + m) * (size_t)Nc + nn2;
            if (OM == 2) ((float*)out)[oi] = v;
            else if (OM == 1) ((bf16*)out)[oi] = __float2bfloat16(v);
            else {
                if (f) ((bf16*)out)[oi] = __float2bfloat16(v);
                else ((float*)out)[oi] = v;
            }
        }
    }
}

// ------- weight transpose + bf16 convert: WT[n][k] = W[k][n] -------
__global__ __launch_bounds__(256) void transpose_k(const void* __restrict__ W,
                                                   u16t* __restrict__ WT,
                                                   int K, int N,
                                                   const int* __restrict__ flagp) {
    int f = *flagp;
    __shared__ u16t T[64][72];
    int n0 = blockIdx.x * 64, k0 = blockIdx.y * 64;
    int t = threadIdx.x;
#pragma unroll
    for (int i = 0; i < 16; i++) {
        int lin = i * 256 + t;
        int kk = lin >> 6, nn = lin & 63;
        T[nn][kk] = f2u(ldFlag(W, (size_t)(k0 + kk) * N + n0 + nn, f));
    }
    __syncthreads();
#pragma unroll
    for (int i = 0; i < 16; i++) {
        int lin = i * 256 + t;
        int nn = lin >> 6, kk = lin & 63;
        WT[(size_t)(n0 + nn) * K + k0 + kk] = T[nn][kk];
    }
}

// ------- MFMA GEMM: C[m][n] = A[m][:] . BT[n][:]  (BT pre-transposed, bf16) -------
// 128x128 tile, 4 waves (2x2), each wave 64x64 via 4x4 frags of 16x16x32.
// AMODE: 0 = A bf16 raw, 1 = LayerNorm A rows on load (mu,rs,g,bb).
// OM: 0 = flag-dispatch out, 1 = bf16 out. GELU: gelu epilogue.
// RES: 0 none, 1 add bf16 resid (ld=N), 2 add LN(A[:,n]) (requires K==N).
template <int AMODE, int OM, bool GELU, int RES>
__global__ __launch_bounds__(256) void gemm_mfma(
    const u16t* __restrict__ A, size_t aBatch,
    const u16t* __restrict__ BT, size_t btBatch,
    const void* __restrict__ bias,
    const u16t* __restrict__ resid, size_t rBatch,
    const float* __restrict__ mu, const float* __restrict__ rs, size_t sBatch,
    const void* __restrict__ g, const void* __restrict__ bb,
    void* __restrict__ out, size_t oBatch, size_t outRow0,
    int K, int N, const int* __restrict__ flagp) {
    int f = *flagp;
    int z = blockIdx.z;
    int t = threadIdx.x;
    int row0 = blockIdx.x * 128, n0 = blockIdx.y * 128;
    __shared__ u16t As[128][72];
    __shared__ u16t Bs[128][72];
    const u16t* Ab = A + (size_t)z * aBatch;
    const u16t* Bb = BT + (size_t)z * btBatch;
    const int sm = t >> 3;        // 0..31
    const int sk = (t & 7) * 8;   // 0..56
    float muv[4], rsv[4];
    if (AMODE == 1) {
#pragma unroll
        for (int i = 0; i < 4; i++) {
            int m = row0 + i * 32 + sm;
            muv[i] = mu[(size_t)z * sBatch + m];
            rsv[i] = rs[(size_t)z * sBatch + m];
        }
    }
    usx8 ra[4], rb[4];
    auto ldstep = [&](int k0) {
#pragma unroll
        for (int i = 0; i < 4; i++) {
            ra[i] = *(const usx8*)&Ab[(size_t)(row0 + i * 32 + sm) * K + k0 + sk];
            rb[i] = *(const usx8*)&Bb[(size_t)(n0 + i * 32 + sm) * K + k0 + sk];
        }
    };
    auto wrstep = [&](int k0) {
#pragma unroll
        for (int i = 0; i < 4; i++) {
            if (AMODE == 1) {
                usx8 v;
#pragma unroll
                for (int j = 0; j < 8; j++) {
                    float x = u2f(ra[i][j]);
                    x = (x - muv[i]) * rsv[i] * ldFlag(g, k0 + sk + j, f) + ldFlag(bb, k0 + sk + j, f);
                    v[j] = f2u(x);
                }
                *(usx8*)&As[i * 32 + sm][sk] = v;
            } else {
                *(usx8*)&As[i * 32 + sm][sk] = ra[i];
            }
            *(usx8*)&Bs[i * 32 + sm][sk] = rb[i];
        }
    };
    fx4 acc[4][4];
    fx4 zz = {0.f, 0.f, 0.f, 0.f};
#pragma unroll
    for (int i = 0; i < 4; i++)
#pragma unroll
        for (int j = 0; j < 4; j++) acc[i][j] = zz;
    int lane = t & 63, w = t >> 6;
    int wr = (w >> 1) * 64, wc = (w & 1) * 64;
    int lr = lane & 15, lg = lane >> 4;
    ldstep(0);
    wrstep(0);
    __syncthreads();
    int KT = K / 64;
    for (int kt = 0; kt < KT; kt++) {
        if (kt + 1 < KT) ldstep((kt + 1) * 64);
#pragma unroll
        for (int ks = 0; ks < 2; ks++) {
            usx8 af[4], bfv[4];
#pragma unroll
            for (int r = 0; r < 4; r++)
                af[r] = *(const usx8*)&As[wr + r * 16 + lr][ks * 32 + lg * 8];
#pragma unroll
            for (int c = 0; c < 4; c++)
                bfv[c] = *(const usx8*)&Bs[wc + c * 16 + lr][ks * 32 + lg * 8];
#pragma unroll
            for (int r = 0; r < 4; r++)
#pragma unroll
                for (int c = 0; c < 4; c++)
                    acc[r][c] = mfma16(af[r], bfv[c], acc[r][c]);
        }
        __syncthreads();
        if (kt + 1 < KT) {
            wrstep((kt + 1) * 64);
            __syncthreads();
        }
    }
#pragma unroll
    for (int r = 0; r < 4; r++) {
#pragma unroll
        for (int c = 0; c < 4; c++) {
            int gc = n0 + wc + c * 16 + lr;
            float bv = bias ? ldFlag(bias, gc, f) : 0.0f;
#pragma unroll
            for (int q = 0; q < 4; q++) {
                int m = row0 + wr + r * 16 + lg * 4 + q;
                float v = acc[r][c][q] + bv;
                if (GELU) v = 0.5f * v * (1.0f + erff(v * 0.70710678118654752f));
                if (RES == 1) v += u2f(resid[(size_t)z * rBatch + (size_t)m * N + gc]);
                if (RES == 2) {
                    float a = u2f(Ab[(size_t)m * K + gc]);
                    float m2 = mu[(size_t)z * sBatch + m], r2 = rs[(size_t)z * sBatch + m];
                    v += (a - m2) * r2 * ldFlag(g, gc, f) + ldFlag(bb, gc, f);
                }
                size_t oi = (size_t)z * oBatch + (outRow0 + m) * (size_t)N + gc;
                if (OM == 1) ((u16t*)out)[oi] = f2u(v);
                else {
                    if (f) ((u16t*)out)[oi] = f2u(v);
                    else ((float*)out)[oi] = v;
                }
            }
        }
    }
}

// ------- MFMA gram split-K: Gp[b][sp] += LN(sc)^T LN(sc) over 1024 rows -------
// Tile 128(ci) x 128(cj); operands staged transposed [channel][n] with XOR swizzle.
__global__ __launch_bounds__(256) void gram_mfma(const u16t* __restrict__ sc,
                                                 const float* __restrict__ mu,
                                                 const float* __restrict__ rs,
                                                 const void* __restrict__ g,
                                                 const void* __restrict__ bb,
                                                 float* __restrict__ Gp,
                                                 const int* __restrict__ flagp) {
    int f = *flagp;
    int bx = blockIdx.x, sp = blockIdx.y, b = blockIdx.z;
    int ci0 = (bx / 3) * 128, cj0 = (bx % 3) * 128;
    __shared__ u16t As[128][72];
    __shared__ u16t Bs[128][72];
    int t = threadIdx.x;
    const int scc = (t * 8) & 127;  // fixed channel offset per thread
    const int snn = t >> 4;         // 0..15
    float ga[8], ba[8], gb[8], bv[8];
#pragma unroll
    for (int j = 0; j < 8; j++) {
        ga[j] = ldFlag(g, ci0 + scc + j, f);
        ba[j] = ldFlag(bb, ci0 + scc + j, f);
        gb[j] = ldFlag(g, cj0 + scc + j, f);
        bv[j] = ldFlag(bb, cj0 + scc + j, f);
    }
    const int RPS = Nn / NS;  // 1024
    int rowbase = b * Nn + sp * RPS;
    usx8 ra[4], rb[4];
    float muv[4], rsv[4];
    auto ldstep = [&](int nn0) {
#pragma unroll
        for (int i = 0; i < 4; i++) {
            int r = rowbase + nn0 + i * 16 + snn;
            ra[i] = *(const usx8*)&sc[(size_t)r * Cc + ci0 + scc];
            rb[i] = *(const usx8*)&sc[(size_t)r * Cc + cj0 + scc];
            muv[i] = mu[r];
            rsv[i] = rs[r];
        }
    };
    auto wrstep = [&]() {
#pragma unroll
        for (int i = 0; i < 4; i++) {
            int n = i * 16 + snn;
            int q = n >> 3, nl = n & 7;
#pragma unroll
            for (int j = 0; j < 8; j++) {
                int c = scc + j;
                int swz = ((c >> 3) ^ (c >> 6)) & 7;
                int po = ((q ^ swz) << 3) + nl;
                As[c][po] = f2u((u2f(ra[i][j]) - muv[i]) * rsv[i] * ga[j] + ba[j]);
                Bs[c][po] = f2u((u2f(rb[i][j]) - muv[i]) * rsv[i] * gb[j] + bv[j]);
            }
        }
    };
    fx4 acc[4][4];
    fx4 zz = {0.f, 0.f, 0.f, 0.f};
#pragma unroll
    for (int i = 0; i < 4; i++)
#pragma unroll
        for (int j = 0; j < 4; j++) acc[i][j] = zz;
    int lane = t & 63, w = t >> 6;
    int wr = (w >> 1) * 64, wc = (w & 1) * 64;
    int lr = lane & 15, lg = lane >> 4;
    ldstep(0);
    wrstep();
    __syncthreads();
    const int KT = RPS / 64;  // 16
    for (int kt = 0; kt < KT; kt++) {
        if (kt + 1 < KT) ldstep((kt + 1) * 64);
#pragma unroll
        for (int ks = 0; ks < 2; ks++) {
            usx8 af[4], bfv[4];
#pragma unroll
            for (int r = 0; r < 4; r++) {
                int ch = wr + r * 16 + lr;
                int swz = ((ch >> 3) ^ (ch >> 6)) & 7;
                af[r] = *(const usx8*)&As[ch][((ks * 4 + lg) ^ swz) << 3];
            }
#pragma unroll
            for (int c = 0; c < 4; c++) {
                int ch = wc + c * 16 + lr;
                int swz = ((ch >> 3) ^ (ch >> 6)) & 7;
                bfv[c] = *(const usx8*)&Bs[ch][((ks * 4 + lg) ^ swz) << 3];
            }
#pragma unroll
            for (int r = 0; r < 4; r++)
#pragma unroll
                for (int c = 0; c < 4; c++)
                    acc[r][c] = mfma16(af[r], bfv[c], acc[r][c]);
        }
        __syncthreads();
        if (kt + 1 < KT) {
            wrstep();
            __syncthreads();
        }
    }
    float* dst = Gp + ((size_t)b * NS + sp) * (size_t)Cc * Cc;
#pragma unroll
    for (int r = 0; r < 4; r++)
#pragma unroll
        for (int c = 0; c < 4; c++)
#pragma unroll
            for (int q = 0; q < 4; q++)
                dst[(size_t)(ci0 + wr + r * 16 + lg * 4 + q) * Cc + cj0 + wc + c * 16 + lr] =
                    acc[r][c][q];
}

// ------- S[b,h] = Wk_h^T @ P_b[:, h*48:(h+1)*48]; softmax(scale*S). grid (NH, Bq). -------
__global__ __launch_bounds__(256) void attn_s_k(const float* __restrict__ P,
                                                const void* __restrict__ kv_w,
                                                float* __restrict__ attn,
                                                const int* __restrict__ flagp) {
    int f = *flagp;
    int hd = blockIdx.x;
    int b = blockIdx.y;
    int t = threadIdx.x;
    const float* Pb = P + (size_t)b * Cc * Cc;
    __shared__ float Pc[32][48];
    __shared__ float Wkc[32][48];
    __shared__ float Ss[48][48];
    int obase = t * 9;
    int dj[9], ej[9];
#pragma unroll
    for (int j = 0; j < 9; j++) {
        dj[j] = (obase + j) / 48;
        ej[j] = (obase + j) % 48;
    }
    float acc[9] = {};
    for (int chunk = 0; chunk < 12; chunk++) {
        for (int idx = t; idx < 1536; idx += 256) {
            int r = idx / 48, e = idx % 48;
            int c = chunk * 32 + r;
            Pc[r][e] = Pb[(size_t)c * Cc + hd * 48 + e];
            Wkc[r][e] = ldFlag(kv_w, (size_t)c * 768 + hd * 48 + e, f);
        }
        __syncthreads();
        for (int r = 0; r < 32; r++) {
#pragma unroll
            for (int j = 0; j < 9; j++) acc[j] += Wkc[r][dj[j]] * Pc[r][ej[j]];
        }
        __syncthreads();
    }
#pragma unroll
    for (int j = 0; j < 9; j++) Ss[dj[j]][ej[j]] = acc[j] * SCALE;
    __syncthreads();
    if (t < 48) {
        float m = -1e30f;
#pragma unroll
        for (int e = 0; e < 48; e++) m = fmaxf(m, Ss[t][e]);
        float ex[48];
        float sum = 0;
#pragma unroll
        for (int e = 0; e < 48; e++) {
            ex[e] = expf(Ss[t][e] - m);
            sum += ex[e];
        }
        float inv = 1.0f / sum;
#pragma unroll
        for (int e = 0; e < 48; e++)
            attn[((size_t)b * NH + hd) * 2304 + t * 48 + e] = ex[e] * inv;
    }
}

// ------- Wtilde[b][c][h*48+d] = sum_e Wq[c, h*48+e] * attn[b,h,d,e]. grid (6, NH, Bq). -------
__global__ __launch_bounds__(256) void wtilde_k(const void* __restrict__ q_w,
                                                const float* __restrict__ attn,
                                                bf16* __restrict__ Wt_,
                                                const int* __restrict__ flagp) {
    int f = *flagp;
    int c0 = blockIdx.x * 64;
    int hd = blockIdx.y;
    int b = blockIdx.z;
    int t = threadIdx.x;
    __shared__ float at[48][48];
    __shared__ float wq[64][48];
    const float* ab = attn + ((size_t)b * NH + hd) * 2304;
    for (int o = t; o < 2304; o += 256) at[o / 48][o % 48] = ab[o];
    for (int o = t; o < 3072; o += 256) {
        int cc = o / 48, e = o % 48;
        wq[cc][e] = ldFlag(q_w, (size_t)(c0 + cc) * Cc + hd * 48 + e, f);
    }
    __syncthreads();
    bf16* outb = Wt_ + (size_t)b * Cc * Cc;
    for (int o = t; o < 3072; o += 256) {
        int cc = o / 48, d = o % 48;
        float s = 0;
#pragma unroll
        for (int e = 0; e < 48; e++) s += wq[cc][e] * at[d][e];
        outb[(size_t)(c0 + cc) * Cc + hd * 48 + d] = __float2bfloat16(s);
    }
}

extern "C" void kernel_launch(void* const* d_in, const int* in_sizes, int n_in,
                              void* d_out, int out_size, void* d_ws, size_t ws_size,
                              hipStream_t stream) {
    (void)in_sizes; (void)n_in; (void)out_size;
    const void* x = d_in[0];
    const void* srcp = d_in[1];
    const void* cpe0_w = d_in[4];
    const void* cpe0_b = d_in[5];
    const void* cpe1_w = d_in[6];
    const void* cpe1_b = d_in[7];
    const void* n1g = d_in[8];
    const void* n1b = d_in[9];
    const void* q_w = d_in[10];
    const void* kv_w = d_in[11];
    const void* proj_w = d_in[12];
    const void* proj_b = d_in[13];
    const void* n2g = d_in[14];
    const void* n2b = d_in[15];
    const void* fc1_w = d_in[16];
    const void* fc1_b = d_in[17];
    const void* fc2_w = d_in[18];
    const void* fc2_b = d_in[19];
    char* ws = (char*)d_ws;

    // ---- workspace layout (53.8 MiB, unchanged footprint) ----
    const size_t CcCc = (size_t)Cc * Cc;
    const size_t NnCc = (size_t)Nn * Cc;
    const size_t SLOT = (size_t)Mrows * Cc * sizeof(bf16);  // 25,165,824
    int* flag = (int*)ws;
    bf16* s0 = (bf16*)(ws + 64);            // scfull -> x2 -> h1c
    bf16* s1 = (bf16*)(ws + 64 + SLOT);     // Gp (18.9MB fp32) -> WeffT (bf16) -> x3
    float* Gp = (float*)s1;
    u16t* WeffT = (u16t*)s1;                // [Bq][384(c_out)][384(c_in)] bf16
    bf16* x3 = s1;
    float* P = (float*)(ws + 64 + 2 * SLOT);        // 4,718,592 [Bq][384x384] fp32
    bf16* Wt_ = (bf16*)P;                           // alias (P dead after attn_s)
    u16t* projT = (u16t*)((char*)P + 2359296);      // [c_out][e] bf16, after attn_s
    u16t* fc1T = (u16t*)P;                          // [1536][384] bf16, after Weff gemm
    u16t* fc2T = (u16t*)((char*)P + 1179648);       // [384][1536] bf16
    float* attnB = (float*)(ws + 64 + 2 * SLOT + 4718592);  // 589,824
    float* muX = (float*)(ws + 64 + 2 * SLOT + 4718592 + 589824);
    float* rsX = muX + Mrows;
    float* mu2 = rsX + Mrows;
    float* rs2 = mu2 + Mrows;
    float* muS = rs2 + Mrows;
    float* rsS = muS + Mrows;
    bf16* scfull = s0;
    bf16* x2 = s0;
    u16t* h1c = (u16t*)s0;  // CR=8192 -> 25.17 MB, exact fit
    const size_t NEED = (size_t)((char*)(rsS + Mrows) - ws);
    if (ws_size < NEED) return;

    bf16* xc = (bf16*)d_out;  // d_out as bf16 scratch (dead before final writes)

    probe_k<<<1, 256, 0, stream>>>(x, flag);

    // 1. xc = cpe0(x) ; LN1 stats
    dwconv_cpe<2, bf16><<<Mrows, 384, 0, stream>>>(x, cpe0_w, cpe0_b, xc, flag);
    rowstats_k<bf16><<<Mrows, 128, 0, stream>>>(xc, muX, rsX);

    // 2. source path: conv -> stats -> MFMA gram partials (LN on load)
    dwconv_cpe<2, bf16><<<Mrows, 384, 0, stream>>>(srcp, cpe0_w, cpe0_b, scfull, flag);
    rowstats_k<bf16><<<Mrows, 128, 0, stream>>>(scfull, muS, rsS);
    gram_mfma<<<dim3(9, NS, Bq), 256, 0, stream>>>((const u16t*)scfull, muS, rsS, n1g, n1b,
                                                   Gp, flag);

    // 3. P_b = (sum_s Gp[b,s]) @ Wv   (fp32 scalar, AR=4; Wv = kv_w cols 384..767)
    gemm_k<0, 2, 2, false, false, 0, NS><<<dim3(6, 6, Bq), 256, 0, stream>>>(
        Gp, (size_t)NS * CcCc, kv_w, 0, 768, 384, nullptr, nullptr, 0,
        nullptr, nullptr, 0, nullptr, nullptr, P, CcCc, 0, Cc, Cc, Cc, flag);

    // 4. attn path + fold into WeffT[c_out][c_in] = (Wt @ proj_w)^T via swapped MFMA gemm
    attn_s_k<<<dim3(NH, Bq), 256, 0, stream>>>(P, kv_w, attnB, flag);
    wtilde_k<<<dim3(6, NH, Bq), 256, 0, stream>>>(q_w, attnB, Wt_, flag);
    transpose_k<<<dim3(6, 6), 256, 0, stream>>>(proj_w, projT, Cc, Cc, flag);
    gemm_mfma<0, 1, false, 0><<<dim3(3, 3, Bq), 256, 0, stream>>>(
        projT, 0, (const u16t*)Wt_, CcCc, nullptr, nullptr, 0,
        nullptr, nullptr, 0, nullptr, nullptr, WeffT, CcCc, 0, Cc, Cc, flag);

    // MLP weight transposes (P region free of Wt_ after Weff gemm; stream-ordered)
    transpose_k<<<dim3(24, 6), 256, 0, stream>>>(fc1_w, fc1T, Cc, CH, flag);
    transpose_k<<<dim3(6, 24), 256, 0, stream>>>(fc2_w, fc2T, CH, Cc, flag);

    // 5. x2 = LN1(xc) + LN1(xc) @ Weff_b + proj_b   (MFMA, LN-on-load + LN residual)
    gemm_mfma<1, 1, false, 2><<<dim3(32, 3, Bq), 256, 0, stream>>>(
        (const u16t*)xc, NnCc, WeffT, CcCc, proj_b, nullptr, 0,
        muX, rsX, Nn, n1g, n1b, x2, NnCc, 0, Cc, Cc, flag);

    // 6. x3 = cpe1(x2) ; LN2 stats
    dwconv_cpe<1, bf16><<<Mrows, 384, 0, stream>>>(x2, cpe1_w, cpe1_b, x3, flag);
    rowstats_k<bf16><<<Mrows, 128, 0, stream>>>(x3, mu2, rs2);

    // 7. MLP in 8192-row chunks: out = x3 + gelu(LN2(x3)@fc1+b1)@fc2+b2
    constexpr int CR = 8192;
    for (int ch = 0; ch < Mrows / CR; ch++) {
        size_t roff = (size_t)ch * CR;
        gemm_mfma<1, 1, true, 0><<<dim3(CR / 128, CH / 128, 1), 256, 0, stream>>>(
            (const u16t*)x3 + roff * Cc, 0, fc1T, 0, fc1_b, nullptr, 0,
            mu2 + roff, rs2 + roff, 0, n2g, n2b, h1c, 0, 0, Cc, CH, flag);
        gemm_mfma<0, 0, false, 1><<<dim3(CR / 128, Cc / 128, 1), 256, 0, stream>>>(
            h1c, 0, fc2T, 0, fc2_b, (const u16t*)x3 + roff * Cc, 0,
            nullptr, nullptr, 0, nullptr, nullptr, d_out, 0, roff, CH, Cc, flag);
    }
}

// Round 2
// 1194.674 us; speedup vs baseline: 3.2498x; 1.3737x over previous
//
#include <hip/hip_runtime.h>
#include <hip/hip_bf16.h>
#include <math.h>

typedef __hip_bfloat16 bf16;
typedef unsigned short u16t;
typedef __bf16 bfx8 __attribute__((ext_vector_type(8)));
typedef float fx4 __attribute__((ext_vector_type(4)));
typedef unsigned short usx8 __attribute__((ext_vector_type(8)));

constexpr int Bq = 8, Hh = 64, Ww = 64, Nn = 4096, Cc = 384, NH = 8, CH = 1536;
constexpr int Mrows = Bq * Nn;  // 32768
constexpr int NS = 4;           // gram split-K factor
constexpr float EPSC = 1e-5f;
constexpr float SCALE = 0.14433756729740643f;  // 48^-0.5

__device__ __forceinline__ float toF(bf16 v) { return __bfloat162float(v); }

__device__ __forceinline__ float ldFlag(const void* p, size_t i, int f) {
    if (f) return __bfloat162float(((const bf16*)p)[i]);
    return ((const float*)p)[i];
}

__device__ __forceinline__ float u2f(u16t u) {
    unsigned int x = ((unsigned int)u) << 16;
    float fv;
    __builtin_memcpy(&fv, &x, 4);
    return fv;
}
__device__ __forceinline__ u16t f2u(float v) {
    bf16 h = __float2bfloat16(v);
    u16t u;
    __builtin_memcpy(&u, &h, 2);
    return u;
}
__device__ __forceinline__ fx4 mfma16(usx8 a, usx8 b, fx4 c) {
    return __builtin_amdgcn_mfma_f32_16x16x32_bf16(
        __builtin_bit_cast(bfx8, a), __builtin_bit_cast(bfx8, b), c, 0, 0, 0);
}

// ---- probe: bf16 N(0,1) data never has exponent>=134 (|v|>=128); fp32 halves do. ----
__global__ __launch_bounds__(256) void probe_k(const void* __restrict__ p, int* __restrict__ flag) {
    int t = threadIdx.x;
    int bad = 0;
    for (int i = t; i < 4096; i += 256) {
        unsigned short u = ((const unsigned short*)p)[i];
        unsigned e = (u >> 7) & 0xFF;
        if (e >= 134) bad++;
    }
    __shared__ int sh[256];
    sh[t] = bad;
    __syncthreads();
    for (int s = 128; s > 0; s >>= 1) {
        if (t < s) sh[t] += sh[t + s];
        __syncthreads();
    }
    if (t == 0) flag[0] = (sh[0] < 64) ? 1 : 0;  // 1 = bf16, 0 = fp32
}

// ---- fused depthwise 3x3 conv + bias + residual + LN row stats ----
// Block = 384 threads (one channel each) x 8 consecutive positions in one image row.
// Each thread loads a 3x10 patch (30 loads -> 8 outputs = 3.75 loads/output) and
// the block reduces mean/var across channels for its 8 complete rows (kills rowstats).
// INM: 1 = internal bf16 input, 2 = raw input via flag.
template <int INM>
__global__ __launch_bounds__(384) void dwconv_stats(const void* __restrict__ xin,
                                                    const void* __restrict__ w,
                                                    const void* __restrict__ bias,
                                                    bf16* __restrict__ out,
                                                    float* __restrict__ mu,
                                                    float* __restrict__ rs,
                                                    const int* __restrict__ flagp) {
    int f = *flagp;
    int c = threadIdx.x;      // channel 0..383
    int w0 = blockIdx.x * 8;  // 0..56
    int hh = blockIdx.y;
    int b = blockIdx.z;
    size_t base = (size_t)b * Nn * Cc;
    float wreg[9];
#pragma unroll
    for (int j = 0; j < 9; j++) wreg[j] = ldFlag(w, c * 9 + j, f);
    float bc = ldFlag(bias, c, f);
    float v[3][10];
#pragma unroll
    for (int ky = 0; ky < 3; ky++) {
        int yy = hh + ky - 1;
        bool rv = (yy >= 0 && yy < Hh);
#pragma unroll
        for (int j = 0; j < 10; j++) {
            int xx = w0 - 1 + j;
            bool cv = (xx >= 0 && xx < Ww);
            float val = 0.f;
            if (rv && cv) {
                size_t idx = base + (size_t)(yy * Ww + xx) * Cc + c;
                val = (INM == 1) ? toF(((const bf16*)xin)[idx]) : ldFlag(xin, idx, f);
            }
            v[ky][j] = val;
        }
    }
    float s[8], s2[8];
#pragma unroll
    for (int p = 0; p < 8; p++) {
        float a = bc;
#pragma unroll
        for (int ky = 0; ky < 3; ky++)
#pragma unroll
            for (int kx = 0; kx < 3; kx++) a += v[ky][p + kx] * wreg[ky * 3 + kx];
        float r = v[1][p + 1] + a;
        size_t oi = base + (size_t)(hh * Ww + w0 + p) * Cc + c;
        out[oi] = __float2bfloat16(r);
        s[p] = r;
        s2[p] = r * r;
    }
#pragma unroll
    for (int off = 32; off > 0; off >>= 1) {
#pragma unroll
        for (int p = 0; p < 8; p++) {
            s[p] += __shfl_down(s[p], off, 64);
            s2[p] += __shfl_down(s2[p], off, 64);
        }
    }
    __shared__ float shS[6][8], shS2[6][8];
    int wv = c >> 6, ln = c & 63;
    if (ln == 0) {
#pragma unroll
        for (int p = 0; p < 8; p++) {
            shS[wv][p] = s[p];
            shS2[wv][p] = s2[p];
        }
    }
    __syncthreads();
    if (c < 8) {
        float S = 0, S2 = 0;
#pragma unroll
        for (int q = 0; q < 6; q++) {
            S += shS[q][c];
            S2 += shS2[q][c];
        }
        float m = S * (1.0f / Cc);
        float var = S2 * (1.0f / Cc) - m * m;
        int row = b * Nn + hh * Ww + w0 + c;
        mu[row] = m;
        rs[row] = rsqrtf(var + EPSC);
    }
}

// ------- scalar tiled GEMM (kept for the small fp32 P = Gsum @ Wv step) -------
template <int AM, int OM, int WM, bool GELU, bool LNA, int RES, int AR>
__global__ __launch_bounds__(256) void gemm_k(const void* __restrict__ A, size_t aBatch,
                                              const void* __restrict__ W, size_t wBatch,
                                              int ldw, int colOff,
                                              const void* __restrict__ bias,
                                              const bf16* __restrict__ resid, size_t rBatch,
                                              const float* __restrict__ mu,
                                              const float* __restrict__ rs, size_t sBatch,
                                              const void* __restrict__ cg,
                                              const void* __restrict__ cb,
                                              void* __restrict__ out, size_t oBatch,
                                              size_t outRow0,
                                              int M, int K, int Nc,
                                              const int* __restrict__ flagp) {
    int f = *flagp;
    int z = blockIdx.z;
    const size_t MK = (size_t)M * K;
    __shared__ float As[16][68];
    __shared__ float Bs[16][68];
    int t = threadIdx.x;
    int tx = t & 15, ty = t >> 4;
    int row0 = blockIdx.x * 64, n0 = blockIdx.y * 64;
    float acc[4][4] = {};
    for (int k0 = 0; k0 < K; k0 += 16) {
#pragma unroll
        for (int i = 0; i < 4; i++) {
            int lin = i * 256 + t;
            int kk = lin & 15, m = lin >> 4;
            size_t ai = (size_t)z * aBatch + (size_t)(row0 + m) * K + k0 + kk;
            float v;
            if (AR > 1) {
                v = 0;
#pragma unroll
                for (int s = 0; s < AR; s++) v += ((const float*)A)[ai + (size_t)s * MK];
            } else {
                v = (AM == 0) ? ((const float*)A)[ai] : toF(((const bf16*)A)[ai]);
            }
            if (LNA) {
                float muv = mu[z * sBatch + row0 + m], rsv = rs[z * sBatch + row0 + m];
                v = (v - muv) * rsv * ldFlag(cg, k0 + kk, f) + ldFlag(cb, k0 + kk, f);
            }
            As[kk][m] = v;
        }
#pragma unroll
        for (int i = 0; i < 4; i++) {
            int lin = i * 256 + t;
            int nn2 = lin & 63, kk = lin >> 6;
            size_t wi = (size_t)z * wBatch + (size_t)(k0 + kk) * ldw + colOff + n0 + nn2;
            Bs[kk][nn2] = (WM == 1) ? toF(((const bf16*)W)[wi]) : ldFlag(W, wi, f);
        }
        __syncthreads();
#pragma unroll
        for (int kk = 0; kk < 16; kk++) {
            float a[4], bv[4];
#pragma unroll
            for (int i = 0; i < 4; i++) a[i] = As[kk][ty * 4 + i];
#pragma unroll
            for (int j = 0; j < 4; j++) bv[j] = Bs[kk][tx * 4 + j];
#pragma unroll
            for (int i = 0; i < 4; i++)
#pragma unroll
                for (int j = 0; j < 4; j++) acc[i][j] += a[i] * bv[j];
        }
        __syncthreads();
    }
#pragma unroll
    for (int i = 0; i < 4; i++) {
        int m = row0 + ty * 4 + i;
#pragma unroll
        for (int j = 0; j < 4; j++) {
            int nn2 = n0 + tx * 4 + j;
            float v = acc[i][j];
            if (bias) v += ldFlag(bias, nn2, f);
            if (GELU) v = 0.5f * v * (1.0f + erff(v * 0.70710678118654752f));
            if (RES == 1) v += toF(resid[(size_t)z * rBatch + (size_t)m * Nc + nn2]);
            if (RES == 2) {
                size_t ai = (size_t)z * aBatch + (size_t)m * K + nn2;
                float a = (AM == 0) ? ((const float*)A)[ai] : toF(((const bf16*)A)[ai]);
                float muv = mu[z * sBatch + m], rsv = rs[z * sBatch + m];
                v += (a - muv) * rsv * ldFlag(cg, nn2, f) + ldFlag(cb, nn2, f);
            }
            size_t oi = (size_t)z * oBatch + (outRow0 + m) * (size_t)Nc + nn2;
            if (OM == 2) ((float*)out)[oi] = v;
            else if (OM == 1) ((bf16*)out)[oi] = __float2bfloat16(v);
            else {
                if (f) ((bf16*)out)[oi] = __float2bfloat16(v);
                else ((float*)out)[oi] = v;
            }
        }
    }
}

// ------- weight transpose + bf16 convert: WT[n][k] = W[k][n] -------
__global__ __launch_bounds__(256) void transpose_k(const void* __restrict__ W,
                                                   u16t* __restrict__ WT,
                                                   int K, int N,
                                                   const int* __restrict__ flagp) {
    int f = *flagp;
    __shared__ u16t T[64][72];
    int n0 = blockIdx.x * 64, k0 = blockIdx.y * 64;
    int t = threadIdx.x;
#pragma unroll
    for (int i = 0; i < 16; i++) {
        int lin = i * 256 + t;
        int kk = lin >> 6, nn = lin & 63;
        T[nn][kk] = f2u(ldFlag(W, (size_t)(k0 + kk) * N + n0 + nn, f));
    }
    __syncthreads();
#pragma unroll
    for (int i = 0; i < 16; i++) {
        int lin = i * 256 + t;
        int nn = lin >> 6, kk = lin & 63;
        WT[(size_t)(n0 + nn) * K + k0 + kk] = T[nn][kk];
    }
}

// ------- MFMA GEMM: C[m][n] = A[m][:] . BT[n][:]  (BT pre-transposed, bf16) -------
template <int AMODE, int OM, bool GELU, int RES>
__global__ __launch_bounds__(256) void gemm_mfma(
    const u16t* __restrict__ A, size_t aBatch,
    const u16t* __restrict__ BT, size_t btBatch,
    const void* __restrict__ bias,
    const u16t* __restrict__ resid, size_t rBatch,
    const float* __restrict__ mu, const float* __restrict__ rs, size_t sBatch,
    const void* __restrict__ g, const void* __restrict__ bb,
    void* __restrict__ out, size_t oBatch, size_t outRow0,
    int K, int N, const int* __restrict__ flagp) {
    int f = *flagp;
    int z = blockIdx.z;
    int t = threadIdx.x;
    int row0 = blockIdx.x * 128, n0 = blockIdx.y * 128;
    __shared__ u16t As[128][72];
    __shared__ u16t Bs[128][72];
    const u16t* Ab = A + (size_t)z * aBatch;
    const u16t* Bb = BT + (size_t)z * btBatch;
    const int sm = t >> 3;        // 0..31
    const int sk = (t & 7) * 8;   // 0..56
    float muv[4], rsv[4];
    if (AMODE == 1) {
#pragma unroll
        for (int i = 0; i < 4; i++) {
            int m = row0 + i * 32 + sm;
            muv[i] = mu[(size_t)z * sBatch + m];
            rsv[i] = rs[(size_t)z * sBatch + m];
        }
    }
    usx8 ra[4], rb[4];
    auto ldstep = [&](int k0) {
#pragma unroll
        for (int i = 0; i < 4; i++) {
            ra[i] = *(const usx8*)&Ab[(size_t)(row0 + i * 32 + sm) * K + k0 + sk];
            rb[i] = *(const usx8*)&Bb[(size_t)(n0 + i * 32 + sm) * K + k0 + sk];
        }
    };
    auto wrstep = [&](int k0) {
#pragma unroll
        for (int i = 0; i < 4; i++) {
            if (AMODE == 1) {
                usx8 v;
#pragma unroll
                for (int j = 0; j < 8; j++) {
                    float x = u2f(ra[i][j]);
                    x = (x - muv[i]) * rsv[i] * ldFlag(g, k0 + sk + j, f) + ldFlag(bb, k0 + sk + j, f);
                    v[j] = f2u(x);
                }
                *(usx8*)&As[i * 32 + sm][sk] = v;
            } else {
                *(usx8*)&As[i * 32 + sm][sk] = ra[i];
            }
            *(usx8*)&Bs[i * 32 + sm][sk] = rb[i];
        }
    };
    fx4 acc[4][4];
    fx4 zz = {0.f, 0.f, 0.f, 0.f};
#pragma unroll
    for (int i = 0; i < 4; i++)
#pragma unroll
        for (int j = 0; j < 4; j++) acc[i][j] = zz;
    int lane = t & 63, w = t >> 6;
    int wr = (w >> 1) * 64, wc = (w & 1) * 64;
    int lr = lane & 15, lg = lane >> 4;
    ldstep(0);
    wrstep(0);
    __syncthreads();
    int KT = K / 64;
    for (int kt = 0; kt < KT; kt++) {
        if (kt + 1 < KT) ldstep((kt + 1) * 64);
#pragma unroll
        for (int ks = 0; ks < 2; ks++) {
            usx8 af[4], bfv[4];
#pragma unroll
            for (int r = 0; r < 4; r++)
                af[r] = *(const usx8*)&As[wr + r * 16 + lr][ks * 32 + lg * 8];
#pragma unroll
            for (int c = 0; c < 4; c++)
                bfv[c] = *(const usx8*)&Bs[wc + c * 16 + lr][ks * 32 + lg * 8];
#pragma unroll
            for (int r = 0; r < 4; r++)
#pragma unroll
                for (int c = 0; c < 4; c++)
                    acc[r][c] = mfma16(af[r], bfv[c], acc[r][c]);
        }
        __syncthreads();
        if (kt + 1 < KT) {
            wrstep((kt + 1) * 64);
            __syncthreads();
        }
    }
#pragma unroll
    for (int r = 0; r < 4; r++) {
#pragma unroll
        for (int c = 0; c < 4; c++) {
            int gc = n0 + wc + c * 16 + lr;
            float bv = bias ? ldFlag(bias, gc, f) : 0.0f;
#pragma unroll
            for (int q = 0; q < 4; q++) {
                int m = row0 + wr + r * 16 + lg * 4 + q;
                float v = acc[r][c][q] + bv;
                if (GELU) v = 0.5f * v * (1.0f + erff(v * 0.70710678118654752f));
                if (RES == 1) v += u2f(resid[(size_t)z * rBatch + (size_t)m * N + gc]);
                if (RES == 2) {
                    float a = u2f(Ab[(size_t)m * K + gc]);
                    float m2 = mu[(size_t)z * sBatch + m], r2 = rs[(size_t)z * sBatch + m];
                    v += (a - m2) * r2 * ldFlag(g, gc, f) + ldFlag(bb, gc, f);
                }
                size_t oi = (size_t)z * oBatch + (outRow0 + m) * (size_t)N + gc;
                if (OM == 1) ((u16t*)out)[oi] = f2u(v);
                else {
                    if (f) ((u16t*)out)[oi] = f2u(v);
                    else ((float*)out)[oi] = v;
                }
            }
        }
    }
}

// ------- MFMA gram split-K: Gp[b][sp] += LN(sc)^T LN(sc) over 1024 rows -------
__global__ __launch_bounds__(256) void gram_mfma(const u16t* __restrict__ sc,
                                                 const float* __restrict__ mu,
                                                 const float* __restrict__ rs,
                                                 const void* __restrict__ g,
                                                 const void* __restrict__ bb,
                                                 float* __restrict__ Gp,
                                                 const int* __restrict__ flagp) {
    int f = *flagp;
    int bx = blockIdx.x, sp = blockIdx.y, b = blockIdx.z;
    int ci0 = (bx / 3) * 128, cj0 = (bx % 3) * 128;
    __shared__ u16t As[128][72];
    __shared__ u16t Bs[128][72];
    int t = threadIdx.x;
    const int scc = (t * 8) & 127;  // fixed channel offset per thread
    const int snn = t >> 4;         // 0..15
    float ga[8], ba[8], gb[8], bv[8];
#pragma unroll
    for (int j = 0; j < 8; j++) {
        ga[j] = ldFlag(g, ci0 + scc + j, f);
        ba[j] = ldFlag(bb, ci0 + scc + j, f);
        gb[j] = ldFlag(g, cj0 + scc + j, f);
        bv[j] = ldFlag(bb, cj0 + scc + j, f);
    }
    const int RPS = Nn / NS;  // 1024
    int rowbase = b * Nn + sp * RPS;
    usx8 ra[4], rb[4];
    float muv[4], rsv[4];
    auto ldstep = [&](int nn0) {
#pragma unroll
        for (int i = 0; i < 4; i++) {
            int r = rowbase + nn0 + i * 16 + snn;
            ra[i] = *(const usx8*)&sc[(size_t)r * Cc + ci0 + scc];
            rb[i] = *(const usx8*)&sc[(size_t)r * Cc + cj0 + scc];
            muv[i] = mu[r];
            rsv[i] = rs[r];
        }
    };
    auto wrstep = [&]() {
#pragma unroll
        for (int i = 0; i < 4; i++) {
            int n = i * 16 + snn;
            int q = n >> 3, nl = n & 7;
#pragma unroll
            for (int j = 0; j < 8; j++) {
                int c = scc + j;
                int swz = ((c >> 3) ^ (c >> 6)) & 7;
                int po = ((q ^ swz) << 3) + nl;
                As[c][po] = f2u((u2f(ra[i][j]) - muv[i]) * rsv[i] * ga[j] + ba[j]);
                Bs[c][po] = f2u((u2f(rb[i][j]) - muv[i]) * rsv[i] * gb[j] + bv[j]);
            }
        }
    };
    fx4 acc[4][4];
    fx4 zz = {0.f, 0.f, 0.f, 0.f};
#pragma unroll
    for (int i = 0; i < 4; i++)
#pragma unroll
        for (int j = 0; j < 4; j++) acc[i][j] = zz;
    int lane = t & 63, w = t >> 6;
    int wr = (w >> 1) * 64, wc = (w & 1) * 64;
    int lr = lane & 15, lg = lane >> 4;
    ldstep(0);
    wrstep();
    __syncthreads();
    const int KT = RPS / 64;  // 16
    for (int kt = 0; kt < KT; kt++) {
        if (kt + 1 < KT) ldstep((kt + 1) * 64);
#pragma unroll
        for (int ks = 0; ks < 2; ks++) {
            usx8 af[4], bfv[4];
#pragma unroll
            for (int r = 0; r < 4; r++) {
                int ch = wr + r * 16 + lr;
                int swz = ((ch >> 3) ^ (ch >> 6)) & 7;
                af[r] = *(const usx8*)&As[ch][((ks * 4 + lg) ^ swz) << 3];
            }
#pragma unroll
            for (int c = 0; c < 4; c++) {
                int ch = wc + c * 16 + lr;
                int swz = ((ch >> 3) ^ (ch >> 6)) & 7;
                bfv[c] = *(const usx8*)&Bs[ch][((ks * 4 + lg) ^ swz) << 3];
            }
#pragma unroll
            for (int r = 0; r < 4; r++)
#pragma unroll
                for (int c = 0; c < 4; c++)
                    acc[r][c] = mfma16(af[r], bfv[c], acc[r][c]);
        }
        __syncthreads();
        if (kt + 1 < KT) {
            wrstep();
            __syncthreads();
        }
    }
    float* dst = Gp + ((size_t)b * NS + sp) * (size_t)Cc * Cc;
#pragma unroll
    for (int r = 0; r < 4; r++)
#pragma unroll
        for (int c = 0; c < 4; c++)
#pragma unroll
            for (int q = 0; q < 4; q++)
                dst[(size_t)(ci0 + wr + r * 16 + lg * 4 + q) * Cc + cj0 + wc + c * 16 + lr] =
                    acc[r][c][q];
}

// ------- S[b,h] = Wk_h^T @ P_b[:, h*48:(h+1)*48]; softmax(scale*S). grid (NH, Bq). -------
__global__ __launch_bounds__(256) void attn_s_k(const float* __restrict__ P,
                                                const void* __restrict__ kv_w,
                                                float* __restrict__ attn,
                                                const int* __restrict__ flagp) {
    int f = *flagp;
    int hd = blockIdx.x;
    int b = blockIdx.y;
    int t = threadIdx.x;
    const float* Pb = P + (size_t)b * Cc * Cc;
    __shared__ float Pc[32][48];
    __shared__ float Wkc[32][48];
    __shared__ float Ss[48][48];
    int obase = t * 9;
    int dj[9], ej[9];
#pragma unroll
    for (int j = 0; j < 9; j++) {
        dj[j] = (obase + j) / 48;
        ej[j] = (obase + j) % 48;
    }
    float acc[9] = {};
    for (int chunk = 0; chunk < 12; chunk++) {
        for (int idx = t; idx < 1536; idx += 256) {
            int r = idx / 48, e = idx % 48;
            int c = chunk * 32 + r;
            Pc[r][e] = Pb[(size_t)c * Cc + hd * 48 + e];
            Wkc[r][e] = ldFlag(kv_w, (size_t)c * 768 + hd * 48 + e, f);
        }
        __syncthreads();
        for (int r = 0; r < 32; r++) {
#pragma unroll
            for (int j = 0; j < 9; j++) acc[j] += Wkc[r][dj[j]] * Pc[r][ej[j]];
        }
        __syncthreads();
    }
#pragma unroll
    for (int j = 0; j < 9; j++) Ss[dj[j]][ej[j]] = acc[j] * SCALE;
    __syncthreads();
    if (t < 48) {
        float m = -1e30f;
#pragma unroll
        for (int e = 0; e < 48; e++) m = fmaxf(m, Ss[t][e]);
        float ex[48];
        float sum = 0;
#pragma unroll
        for (int e = 0; e < 48; e++) {
            ex[e] = expf(Ss[t][e] - m);
            sum += ex[e];
        }
        float inv = 1.0f / sum;
#pragma unroll
        for (int e = 0; e < 48; e++)
            attn[((size_t)b * NH + hd) * 2304 + t * 48 + e] = ex[e] * inv;
    }
}

// ------- Wtilde[b][c][h*48+d] = sum_e Wq[c, h*48+e] * attn[b,h,d,e]. grid (6, NH, Bq). -------
__global__ __launch_bounds__(256) void wtilde_k(const void* __restrict__ q_w,
                                                const float* __restrict__ attn,
                                                bf16* __restrict__ Wt_,
                                                const int* __restrict__ flagp) {
    int f = *flagp;
    int c0 = blockIdx.x * 64;
    int hd = blockIdx.y;
    int b = blockIdx.z;
    int t = threadIdx.x;
    __shared__ float at[48][48];
    __shared__ float wq[64][48];
    const float* ab = attn + ((size_t)b * NH + hd) * 2304;
    for (int o = t; o < 2304; o += 256) at[o / 48][o % 48] = ab[o];
    for (int o = t; o < 3072; o += 256) {
        int cc = o / 48, e = o % 48;
        wq[cc][e] = ldFlag(q_w, (size_t)(c0 + cc) * Cc + hd * 48 + e, f);
    }
    __syncthreads();
    bf16* outb = Wt_ + (size_t)b * Cc * Cc;
    for (int o = t; o < 3072; o += 256) {
        int cc = o / 48, d = o % 48;
        float s = 0;
#pragma unroll
        for (int e = 0; e < 48; e++) s += wq[cc][e] * at[d][e];
        outb[(size_t)(c0 + cc) * Cc + hd * 48 + d] = __float2bfloat16(s);
    }
}

extern "C" void kernel_launch(void* const* d_in, const int* in_sizes, int n_in,
                              void* d_out, int out_size, void* d_ws, size_t ws_size,
                              hipStream_t stream) {
    (void)in_sizes; (void)n_in; (void)out_size;
    const void* x = d_in[0];
    const void* srcp = d_in[1];
    const void* cpe0_w = d_in[4];
    const void* cpe0_b = d_in[5];
    const void* cpe1_w = d_in[6];
    const void* cpe1_b = d_in[7];
    const void* n1g = d_in[8];
    const void* n1b = d_in[9];
    const void* q_w = d_in[10];
    const void* kv_w = d_in[11];
    const void* proj_w = d_in[12];
    const void* proj_b = d_in[13];
    const void* n2g = d_in[14];
    const void* n2b = d_in[15];
    const void* fc1_w = d_in[16];
    const void* fc1_b = d_in[17];
    const void* fc2_w = d_in[18];
    const void* fc2_b = d_in[19];
    char* ws = (char*)d_ws;

    // ---- workspace layout (unchanged footprint) ----
    const size_t CcCc = (size_t)Cc * Cc;
    const size_t NnCc = (size_t)Nn * Cc;
    const size_t SLOT = (size_t)Mrows * Cc * sizeof(bf16);  // 25,165,824
    int* flag = (int*)ws;
    bf16* s0 = (bf16*)(ws + 64);            // scfull -> x2 -> h1c
    bf16* s1 = (bf16*)(ws + 64 + SLOT);     // Gp (18.9MB fp32) -> WeffT (bf16) -> x3
    float* Gp = (float*)s1;
    u16t* WeffT = (u16t*)s1;                // [Bq][384(c_out)][384(c_in)] bf16
    bf16* x3 = s1;
    float* P = (float*)(ws + 64 + 2 * SLOT);        // 4,718,592 [Bq][384x384] fp32
    bf16* Wt_ = (bf16*)P;                           // alias (P dead after attn_s)
    u16t* projT = (u16t*)((char*)P + 2359296);      // [c_out][e] bf16, after attn_s
    u16t* fc1T = (u16t*)P;                          // [1536][384] bf16, after Weff gemm
    u16t* fc2T = (u16t*)((char*)P + 1179648);       // [384][1536] bf16
    float* attnB = (float*)(ws + 64 + 2 * SLOT + 4718592);  // 589,824
    float* muX = (float*)(ws + 64 + 2 * SLOT + 4718592 + 589824);
    float* rsX = muX + Mrows;
    float* mu2 = rsX + Mrows;
    float* rs2 = mu2 + Mrows;
    float* muS = rs2 + Mrows;
    float* rsS = muS + Mrows;
    bf16* scfull = s0;
    bf16* x2 = s0;
    u16t* h1c = (u16t*)s0;  // CR=8192 -> 25.17 MB, exact fit
    const size_t NEED = (size_t)((char*)(rsS + Mrows) - ws);
    if (ws_size < NEED) return;

    bf16* xc = (bf16*)d_out;  // d_out as bf16 scratch (dead before final writes)

    probe_k<<<1, 256, 0, stream>>>(x, flag);

    // 1. xc = cpe0(x) + LN1 stats (fused)
    dwconv_stats<2><<<dim3(Ww / 8, Hh, Bq), 384, 0, stream>>>(x, cpe0_w, cpe0_b, xc,
                                                              muX, rsX, flag);

    // 2. source path: fused conv+stats -> MFMA gram partials (LN on load)
    dwconv_stats<2><<<dim3(Ww / 8, Hh, Bq), 384, 0, stream>>>(srcp, cpe0_w, cpe0_b, scfull,
                                                              muS, rsS, flag);
    gram_mfma<<<dim3(9, NS, Bq), 256, 0, stream>>>((const u16t*)scfull, muS, rsS, n1g, n1b,
                                                   Gp, flag);

    // 3. P_b = (sum_s Gp[b,s]) @ Wv   (fp32 scalar, AR=4; Wv = kv_w cols 384..767)
    gemm_k<0, 2, 2, false, false, 0, NS><<<dim3(6, 6, Bq), 256, 0, stream>>>(
        Gp, (size_t)NS * CcCc, kv_w, 0, 768, 384, nullptr, nullptr, 0,
        nullptr, nullptr, 0, nullptr, nullptr, P, CcCc, 0, Cc, Cc, Cc, flag);

    // 4. attn path + fold into WeffT[c_out][c_in] = (Wt @ proj_w)^T via swapped MFMA gemm
    attn_s_k<<<dim3(NH, Bq), 256, 0, stream>>>(P, kv_w, attnB, flag);
    wtilde_k<<<dim3(6, NH, Bq), 256, 0, stream>>>(q_w, attnB, Wt_, flag);
    transpose_k<<<dim3(6, 6), 256, 0, stream>>>(proj_w, projT, Cc, Cc, flag);
    gemm_mfma<0, 1, false, 0><<<dim3(3, 3, Bq), 256, 0, stream>>>(
        projT, 0, (const u16t*)Wt_, CcCc, nullptr, nullptr, 0,
        nullptr, nullptr, 0, nullptr, nullptr, WeffT, CcCc, 0, Cc, Cc, flag);

    // MLP weight transposes (P region free of Wt_ after Weff gemm; stream-ordered)
    transpose_k<<<dim3(24, 6), 256, 0, stream>>>(fc1_w, fc1T, Cc, CH, flag);
    transpose_k<<<dim3(6, 24), 256, 0, stream>>>(fc2_w, fc2T, CH, Cc, flag);

    // 5. x2 = LN1(xc) + LN1(xc) @ Weff_b + proj_b   (MFMA, LN-on-load + LN residual)
    gemm_mfma<1, 1, false, 2><<<dim3(32, 3, Bq), 256, 0, stream>>>(
        (const u16t*)xc, NnCc, WeffT, CcCc, proj_b, nullptr, 0,
        muX, rsX, Nn, n1g, n1b, x2, NnCc, 0, Cc, Cc, flag);

    // 6. x3 = cpe1(x2) + LN2 stats (fused)
    dwconv_stats<1><<<dim3(Ww / 8, Hh, Bq), 384, 0, stream>>>(x2, cpe1_w, cpe1_b, x3,
                                                              mu2, rs2, flag);

    // 7. MLP in 8192-row chunks: out = x3 + gelu(LN2(x3)@fc1+b1)@fc2+b2
    constexpr int CR = 8192;
    for (int ch = 0; ch < Mrows / CR; ch++) {
        size_t roff = (size_t)ch * CR;
        gemm_mfma<1, 1, true, 0><<<dim3(CR / 128, CH / 128, 1), 256, 0, stream>>>(
            (const u16t*)x3 + roff * Cc, 0, fc1T, 0, fc1_b, nullptr, 0,
            mu2 + roff, rs2 + roff, 0, n2g, n2b, h1c, 0, 0, Cc, CH, flag);
        gemm_mfma<0, 0, false, 1><<<dim3(CR / 128, Cc / 128, 1), 256, 0, stream>>>(
            h1c, 0, fc2T, 0, fc2_b, (const u16t*)x3 + roff * Cc, 0,
            nullptr, nullptr, 0, nullptr, nullptr, d_out, 0, roff, CH, Cc, flag);
    }
}

// Round 3
// 861.391 us; speedup vs baseline: 4.5072x; 1.3869x over previous
//
#include <hip/hip_runtime.h>
#include <hip/hip_bf16.h>
#include <math.h>

typedef __hip_bfloat16 bf16;
typedef unsigned short u16t;
typedef __bf16 bfx8 __attribute__((ext_vector_type(8)));
typedef float fx4 __attribute__((ext_vector_type(4)));
typedef unsigned short usx8 __attribute__((ext_vector_type(8)));

constexpr int Bq = 8, Hh = 64, Ww = 64, Nn = 4096, Cc = 384, NH = 8, CH = 1536;
constexpr int Mrows = Bq * Nn;  // 32768
constexpr int NS = 4;           // gram split-K factor
constexpr float EPSC = 1e-5f;
constexpr float SCALE = 0.14433756729740643f;  // 48^-0.5

__device__ __forceinline__ float toF(bf16 v) { return __bfloat162float(v); }

__device__ __forceinline__ float ldFlag(const void* p, size_t i, int f) {
    if (f) return __bfloat162float(((const bf16*)p)[i]);
    return ((const float*)p)[i];
}

__device__ __forceinline__ float u2f(u16t u) {
    unsigned int x = ((unsigned int)u) << 16;
    float fv;
    __builtin_memcpy(&fv, &x, 4);
    return fv;
}
__device__ __forceinline__ u16t f2u(float v) {
    bf16 h = __float2bfloat16(v);
    u16t u;
    __builtin_memcpy(&u, &h, 2);
    return u;
}
__device__ __forceinline__ fx4 mfma16(usx8 a, usx8 b, fx4 c) {
    return __builtin_amdgcn_mfma_f32_16x16x32_bf16(
        __builtin_bit_cast(bfx8, a), __builtin_bit_cast(bfx8, b), c, 0, 0, 0);
}

// ---- probe: bf16 N(0,1) data never has exponent>=134 (|v|>=128); fp32 halves do. ----
__global__ __launch_bounds__(256) void probe_k(const void* __restrict__ p, int* __restrict__ flag) {
    int t = threadIdx.x;
    int bad = 0;
    for (int i = t; i < 4096; i += 256) {
        unsigned short u = ((const unsigned short*)p)[i];
        unsigned e = (u >> 7) & 0xFF;
        if (e >= 134) bad++;
    }
    __shared__ int sh[256];
    sh[t] = bad;
    __syncthreads();
    for (int s = 128; s > 0; s >>= 1) {
        if (t < s) sh[t] += sh[t + s];
        __syncthreads();
    }
    if (t == 0) flag[0] = (sh[0] < 64) ? 1 : 0;  // 1 = bf16, 0 = fp32
}

// ---- bf16 copies of LN2 gamma/beta for vectorized LN-on-load in fc1 ----
__global__ __launch_bounds__(384) void prep_k(const void* __restrict__ g,
                                              const void* __restrict__ b,
                                              u16t* __restrict__ gB, u16t* __restrict__ bB,
                                              const int* __restrict__ flagp) {
    int f = *flagp;
    int t = threadIdx.x;
    gB[t] = f2u(ldFlag(g, t, f));
    bB[t] = f2u(ldFlag(b, t, f));
}

// ---- fused depthwise 3x3 conv + bias + residual (+LN normalize OR +stats) ----
// Block = 384 threads (one channel each) x 8 consecutive positions in one image row.
// MODE 0: write LayerNorm'd output only (needs g, bb). MODE 1: write raw + mu/rs stats.
// INM: 1 = internal bf16 input, 2 = raw input via flag.
template <int INM, int MODE>
__global__ __launch_bounds__(384) void dwconv_ln(const void* __restrict__ xin,
                                                 const void* __restrict__ w,
                                                 const void* __restrict__ bias,
                                                 bf16* __restrict__ out,
                                                 const void* __restrict__ g,
                                                 const void* __restrict__ bb,
                                                 float* __restrict__ mu,
                                                 float* __restrict__ rs,
                                                 const int* __restrict__ flagp) {
    int f = *flagp;
    int c = threadIdx.x;      // channel 0..383
    int w0 = blockIdx.x * 8;  // 0..56
    int hh = blockIdx.y;
    int b = blockIdx.z;
    size_t base = (size_t)b * Nn * Cc;
    float wreg[9];
#pragma unroll
    for (int j = 0; j < 9; j++) wreg[j] = ldFlag(w, c * 9 + j, f);
    float bc = ldFlag(bias, c, f);
    float v[3][10];
#pragma unroll
    for (int ky = 0; ky < 3; ky++) {
        int yy = hh + ky - 1;
        bool rv = (yy >= 0 && yy < Hh);
#pragma unroll
        for (int j = 0; j < 10; j++) {
            int xx = w0 - 1 + j;
            bool cv = (xx >= 0 && xx < Ww);
            float val = 0.f;
            if (rv && cv) {
                size_t idx = base + (size_t)(yy * Ww + xx) * Cc + c;
                val = (INM == 1) ? toF(((const bf16*)xin)[idx]) : ldFlag(xin, idx, f);
            }
            v[ky][j] = val;
        }
    }
    float r[8], s[8], s2[8];
#pragma unroll
    for (int p = 0; p < 8; p++) {
        float a = bc;
#pragma unroll
        for (int ky = 0; ky < 3; ky++)
#pragma unroll
            for (int kx = 0; kx < 3; kx++) a += v[ky][p + kx] * wreg[ky * 3 + kx];
        r[p] = v[1][p + 1] + a;
        s[p] = r[p];
        s2[p] = r[p] * r[p];
    }
#pragma unroll
    for (int off = 32; off > 0; off >>= 1) {
#pragma unroll
        for (int p = 0; p < 8; p++) {
            s[p] += __shfl_down(s[p], off, 64);
            s2[p] += __shfl_down(s2[p], off, 64);
        }
    }
    __shared__ float shS[6][8], shS2[6][8];
    __shared__ float shMu[8], shRs[8];
    int wv = c >> 6, ln = c & 63;
    if (ln == 0) {
#pragma unroll
        for (int p = 0; p < 8; p++) {
            shS[wv][p] = s[p];
            shS2[wv][p] = s2[p];
        }
    }
    __syncthreads();
    if (c < 8) {
        float S = 0, S2 = 0;
#pragma unroll
        for (int q = 0; q < 6; q++) {
            S += shS[q][c];
            S2 += shS2[q][c];
        }
        float m = S * (1.0f / Cc);
        float var = S2 * (1.0f / Cc) - m * m;
        float rr = rsqrtf(var + EPSC);
        if (MODE == 0) {
            shMu[c] = m;
            shRs[c] = rr;
        } else {
            int row = b * Nn + hh * Ww + w0 + c;
            mu[row] = m;
            rs[row] = rr;
        }
    }
    if (MODE == 0) {
        __syncthreads();
        float gc = ldFlag(g, c, f), bbc = ldFlag(bb, c, f);
#pragma unroll
        for (int p = 0; p < 8; p++) {
            size_t oi = base + (size_t)(hh * Ww + w0 + p) * Cc + c;
            out[oi] = __float2bfloat16((r[p] - shMu[p]) * shRs[p] * gc + bbc);
        }
    } else {
#pragma unroll
        for (int p = 0; p < 8; p++) {
            size_t oi = base + (size_t)(hh * Ww + w0 + p) * Cc + c;
            out[oi] = __float2bfloat16(r[p]);
        }
    }
}

// ------- scalar tiled GEMM (kept for the small fp32 P = Gsum @ Wv step) -------
template <int AM, int OM, int WM, bool GELU, bool LNA, int RES, int AR>
__global__ __launch_bounds__(256) void gemm_k(const void* __restrict__ A, size_t aBatch,
                                              const void* __restrict__ W, size_t wBatch,
                                              int ldw, int colOff,
                                              const void* __restrict__ bias,
                                              const bf16* __restrict__ resid, size_t rBatch,
                                              const float* __restrict__ mu,
                                              const float* __restrict__ rs, size_t sBatch,
                                              const void* __restrict__ cg,
                                              const void* __restrict__ cb,
                                              void* __restrict__ out, size_t oBatch,
                                              size_t outRow0,
                                              int M, int K, int Nc,
                                              const int* __restrict__ flagp) {
    int f = *flagp;
    int z = blockIdx.z;
    const size_t MK = (size_t)M * K;
    __shared__ float As[16][68];
    __shared__ float Bs[16][68];
    int t = threadIdx.x;
    int tx = t & 15, ty = t >> 4;
    int row0 = blockIdx.x * 64, n0 = blockIdx.y * 64;
    float acc[4][4] = {};
    for (int k0 = 0; k0 < K; k0 += 16) {
#pragma unroll
        for (int i = 0; i < 4; i++) {
            int lin = i * 256 + t;
            int kk = lin & 15, m = lin >> 4;
            size_t ai = (size_t)z * aBatch + (size_t)(row0 + m) * K + k0 + kk;
            float v;
            if (AR > 1) {
                v = 0;
#pragma unroll
                for (int s = 0; s < AR; s++) v += ((const float*)A)[ai + (size_t)s * MK];
            } else {
                v = (AM == 0) ? ((const float*)A)[ai] : toF(((const bf16*)A)[ai]);
            }
            if (LNA) {
                float muv = mu[z * sBatch + row0 + m], rsv = rs[z * sBatch + row0 + m];
                v = (v - muv) * rsv * ldFlag(cg, k0 + kk, f) + ldFlag(cb, k0 + kk, f);
            }
            As[kk][m] = v;
        }
#pragma unroll
        for (int i = 0; i < 4; i++) {
            int lin = i * 256 + t;
            int nn2 = lin & 63, kk = lin >> 6;
            size_t wi = (size_t)z * wBatch + (size_t)(k0 + kk) * ldw + colOff + n0 + nn2;
            Bs[kk][nn2] = (WM == 1) ? toF(((const bf16*)W)[wi]) : ldFlag(W, wi, f);
        }
        __syncthreads();
#pragma unroll
        for (int kk = 0; kk < 16; kk++) {
            float a[4], bv[4];
#pragma unroll
            for (int i = 0; i < 4; i++) a[i] = As[kk][ty * 4 + i];
#pragma unroll
            for (int j = 0; j < 4; j++) bv[j] = Bs[kk][tx * 4 + j];
#pragma unroll
            for (int i = 0; i < 4; i++)
#pragma unroll
                for (int j = 0; j < 4; j++) acc[i][j] += a[i] * bv[j];
        }
        __syncthreads();
    }
#pragma unroll
    for (int i = 0; i < 4; i++) {
        int m = row0 + ty * 4 + i;
#pragma unroll
        for (int j = 0; j < 4; j++) {
            int nn2 = n0 + tx * 4 + j;
            float v = acc[i][j];
            if (bias) v += ldFlag(bias, nn2, f);
            if (GELU) v = 0.5f * v * (1.0f + erff(v * 0.70710678118654752f));
            if (RES == 1) v += toF(resid[(size_t)z * rBatch + (size_t)m * Nc + nn2]);
            size_t oi = (size_t)z * oBatch + (outRow0 + m) * (size_t)Nc + nn2;
            if (OM == 2) ((float*)out)[oi] = v;
            else if (OM == 1) ((bf16*)out)[oi] = __float2bfloat16(v);
            else {
                if (f) ((bf16*)out)[oi] = __float2bfloat16(v);
                else ((float*)out)[oi] = v;
            }
        }
    }
}

// ------- weight transpose + bf16 convert: WT[n][k] = W[k][n] -------
__global__ __launch_bounds__(256) void transpose_k(const void* __restrict__ W,
                                                   u16t* __restrict__ WT,
                                                   int K, int N,
                                                   const int* __restrict__ flagp) {
    int f = *flagp;
    __shared__ u16t T[64][72];
    int n0 = blockIdx.x * 64, k0 = blockIdx.y * 64;
    int t = threadIdx.x;
#pragma unroll
    for (int i = 0; i < 16; i++) {
        int lin = i * 256 + t;
        int kk = lin >> 6, nn = lin & 63;
        T[nn][kk] = f2u(ldFlag(W, (size_t)(k0 + kk) * N + n0 + nn, f));
    }
    __syncthreads();
#pragma unroll
    for (int i = 0; i < 16; i++) {
        int lin = i * 256 + t;
        int nn = lin >> 6, kk = lin & 63;
        WT[(size_t)(n0 + nn) * K + k0 + kk] = T[nn][kk];
    }
}

// ------- MFMA GEMM: C[m][n] = A[m][:] . BT[n][:]  (BT pre-transposed, bf16) -------
// 128x128 tile, 4 waves (2x2), 16B-chunk XOR-swizzled [128][64] LDS (32 KB total).
// AMODE: 0 = plain bf16 A; 1 = LN on load with bf16 gamma/beta vector loads.
// OM: 0 = flag-dispatch out, 1 = bf16 out. RES: 0 none, 1 bf16 resid ptr, 2 add A[m][n] (K==N).
template <int AMODE, int OM, bool GELU, int RES>
__global__ __launch_bounds__(256) void gemm_mfma(
    const u16t* __restrict__ A, size_t aBatch,
    const u16t* __restrict__ BT, size_t btBatch,
    const void* __restrict__ bias,
    const u16t* __restrict__ resid, size_t rBatch,
    const float* __restrict__ mu, const float* __restrict__ rs, size_t sBatch,
    const u16t* __restrict__ gbf, const u16t* __restrict__ bbf,
    void* __restrict__ out, size_t oBatch, size_t outRow0,
    int K, int N, const int* __restrict__ flagp) {
    int f = *flagp;
    int z = blockIdx.z;
    int t = threadIdx.x;
    int row0 = blockIdx.x * 128, n0 = blockIdx.y * 128;
    __shared__ u16t As[128][64];
    __shared__ u16t Bs[128][64];
    const u16t* Ab = A + (size_t)z * aBatch;
    const u16t* Bb = BT + (size_t)z * btBatch;
    const int sm = t >> 3;    // staging row 0..31 (per i-block of 32)
    const int sk8 = t & 7;    // 16B chunk 0..7
    float muv[4], rsv[4];
    if (AMODE == 1) {
#pragma unroll
        for (int i = 0; i < 4; i++) {
            int m = row0 + i * 32 + sm;
            muv[i] = mu[(size_t)z * sBatch + m];
            rsv[i] = rs[(size_t)z * sBatch + m];
        }
    }
    usx8 ra[4], rb[4];
    auto ldstep = [&](int k0) {
#pragma unroll
        for (int i = 0; i < 4; i++) {
            ra[i] = *(const usx8*)&Ab[(size_t)(row0 + i * 32 + sm) * K + k0 + sk8 * 8];
            rb[i] = *(const usx8*)&Bb[(size_t)(n0 + i * 32 + sm) * K + k0 + sk8 * 8];
        }
    };
    auto wrstep = [&](int k0) {
        usx8 ga, ba;
        if (AMODE == 1) {
            ga = *(const usx8*)&gbf[k0 + sk8 * 8];
            ba = *(const usx8*)&bbf[k0 + sk8 * 8];
        }
#pragma unroll
        for (int i = 0; i < 4; i++) {
            int row = i * 32 + sm;
            int dst = (sk8 ^ (row & 7)) << 3;
            if (AMODE == 1) {
                usx8 v;
#pragma unroll
                for (int j = 0; j < 8; j++)
                    v[j] = f2u((u2f(ra[i][j]) - muv[i]) * rsv[i] * u2f(ga[j]) + u2f(ba[j]));
                *(usx8*)&As[row][dst] = v;
            } else {
                *(usx8*)&As[row][dst] = ra[i];
            }
            *(usx8*)&Bs[row][dst] = rb[i];
        }
    };
    fx4 acc[4][4];
    fx4 zz = {0.f, 0.f, 0.f, 0.f};
#pragma unroll
    for (int i = 0; i < 4; i++)
#pragma unroll
        for (int j = 0; j < 4; j++) acc[i][j] = zz;
    int lane = t & 63, w = t >> 6;
    int wr = (w >> 1) * 64, wc = (w & 1) * 64;
    int lr = lane & 15, lg = lane >> 4;
    ldstep(0);
    wrstep(0);
    __syncthreads();
    int KT = K / 64;
    for (int kt = 0; kt < KT; kt++) {
        if (kt + 1 < KT) ldstep((kt + 1) * 64);
#pragma unroll
        for (int ks = 0; ks < 2; ks++) {
            usx8 af[4], bfv[4];
#pragma unroll
            for (int r = 0; r < 4; r++) {
                int row = wr + r * 16 + lr;
                af[r] = *(const usx8*)&As[row][((4 * ks + lg) ^ (row & 7)) << 3];
            }
#pragma unroll
            for (int c = 0; c < 4; c++) {
                int row = wc + c * 16 + lr;
                bfv[c] = *(const usx8*)&Bs[row][((4 * ks + lg) ^ (row & 7)) << 3];
            }
#pragma unroll
            for (int r = 0; r < 4; r++)
#pragma unroll
                for (int c = 0; c < 4; c++)
                    acc[r][c] = mfma16(af[r], bfv[c], acc[r][c]);
        }
        __syncthreads();
        if (kt + 1 < KT) {
            wrstep((kt + 1) * 64);
            __syncthreads();
        }
    }
#pragma unroll
    for (int r = 0; r < 4; r++) {
#pragma unroll
        for (int c = 0; c < 4; c++) {
            int gc = n0 + wc + c * 16 + lr;
            float bv = bias ? ldFlag(bias, gc, f) : 0.0f;
#pragma unroll
            for (int q = 0; q < 4; q++) {
                int m = row0 + wr + r * 16 + lg * 4 + q;
                float v = acc[r][c][q] + bv;
                if (GELU) v = 0.5f * v * (1.0f + erff(v * 0.70710678118654752f));
                if (RES == 1) v += u2f(resid[(size_t)z * rBatch + (size_t)m * N + gc]);
                if (RES == 2) v += u2f(Ab[(size_t)m * K + gc]);
                size_t oi = (size_t)z * oBatch + (outRow0 + m) * (size_t)N + gc;
                if (OM == 1) ((u16t*)out)[oi] = f2u(v);
                else {
                    if (f) ((u16t*)out)[oi] = f2u(v);
                    else ((float*)out)[oi] = v;
                }
            }
        }
    }
}

// ------- MFMA gram split-K: Gp[b][sp] = lnS^T lnS over 1024 rows (lnS pre-normalized) -------
__global__ __launch_bounds__(256) void gram_mfma(const u16t* __restrict__ sc,
                                                 float* __restrict__ Gp) {
    int bx = blockIdx.x, sp = blockIdx.y, b = blockIdx.z;
    int ci0 = (bx / 3) * 128, cj0 = (bx % 3) * 128;
    __shared__ u16t As[128][72];
    __shared__ u16t Bs[128][72];
    int t = threadIdx.x;
    const int scc = (t * 8) & 127;  // fixed channel offset per thread
    const int snn = t >> 4;         // 0..15
    const int RPS = Nn / NS;        // 1024
    int rowbase = b * Nn + sp * RPS;
    usx8 ra[4], rb[4];
    auto ldstep = [&](int nn0) {
#pragma unroll
        for (int i = 0; i < 4; i++) {
            int r = rowbase + nn0 + i * 16 + snn;
            ra[i] = *(const usx8*)&sc[(size_t)r * Cc + ci0 + scc];
            rb[i] = *(const usx8*)&sc[(size_t)r * Cc + cj0 + scc];
        }
    };
    auto wrstep = [&]() {
#pragma unroll
        for (int i = 0; i < 4; i++) {
            int n = i * 16 + snn;
            int q = n >> 3, nl = n & 7;
#pragma unroll
            for (int j = 0; j < 8; j++) {
                int c = scc + j;
                int swz = ((c >> 3) ^ (c >> 6)) & 7;
                int po = ((q ^ swz) << 3) + nl;
                As[c][po] = ra[i][j];
                Bs[c][po] = rb[i][j];
            }
        }
    };
    fx4 acc[4][4];
    fx4 zz = {0.f, 0.f, 0.f, 0.f};
#pragma unroll
    for (int i = 0; i < 4; i++)
#pragma unroll
        for (int j = 0; j < 4; j++) acc[i][j] = zz;
    int lane = t & 63, w = t >> 6;
    int wr = (w >> 1) * 64, wc = (w & 1) * 64;
    int lr = lane & 15, lg = lane >> 4;
    ldstep(0);
    wrstep();
    __syncthreads();
    const int KT = RPS / 64;  // 16
    for (int kt = 0; kt < KT; kt++) {
        if (kt + 1 < KT) ldstep((kt + 1) * 64);
#pragma unroll
        for (int ks = 0; ks < 2; ks++) {
            usx8 af[4], bfv[4];
#pragma unroll
            for (int r = 0; r < 4; r++) {
                int ch = wr + r * 16 + lr;
                int swz = ((ch >> 3) ^ (ch >> 6)) & 7;
                af[r] = *(const usx8*)&As[ch][((ks * 4 + lg) ^ swz) << 3];
            }
#pragma unroll
            for (int c = 0; c < 4; c++) {
                int ch = wc + c * 16 + lr;
                int swz = ((ch >> 3) ^ (ch >> 6)) & 7;
                bfv[c] = *(const usx8*)&Bs[ch][((ks * 4 + lg) ^ swz) << 3];
            }
#pragma unroll
            for (int r = 0; r < 4; r++)
#pragma unroll
                for (int c = 0; c < 4; c++)
                    acc[r][c] = mfma16(af[r], bfv[c], acc[r][c]);
        }
        __syncthreads();
        if (kt + 1 < KT) {
            wrstep();
            __syncthreads();
        }
    }
    float* dst = Gp + ((size_t)b * NS + sp) * (size_t)Cc * Cc;
#pragma unroll
    for (int r = 0; r < 4; r++)
#pragma unroll
        for (int c = 0; c < 4; c++)
#pragma unroll
            for (int q = 0; q < 4; q++)
                dst[(size_t)(ci0 + wr + r * 16 + lg * 4 + q) * Cc + cj0 + wc + c * 16 + lr] =
                    acc[r][c][q];
}

// ------- S[b,h] = Wk_h^T @ P_b[:, h*48:(h+1)*48]; softmax(scale*S). grid (NH, Bq). -------
__global__ __launch_bounds__(256) void attn_s_k(const float* __restrict__ P,
                                                const void* __restrict__ kv_w,
                                                float* __restrict__ attn,
                                                const int* __restrict__ flagp) {
    int f = *flagp;
    int hd = blockIdx.x;
    int b = blockIdx.y;
    int t = threadIdx.x;
    const float* Pb = P + (size_t)b * Cc * Cc;
    __shared__ float Pc[32][48];
    __shared__ float Wkc[32][48];
    __shared__ float Ss[48][48];
    int obase = t * 9;
    int dj[9], ej[9];
#pragma unroll
    for (int j = 0; j < 9; j++) {
        dj[j] = (obase + j) / 48;
        ej[j] = (obase + j) % 48;
    }
    float acc[9] = {};
    for (int chunk = 0; chunk < 12; chunk++) {
        for (int idx = t; idx < 1536; idx += 256) {
            int r = idx / 48, e = idx % 48;
            int c = chunk * 32 + r;
            Pc[r][e] = Pb[(size_t)c * Cc + hd * 48 + e];
            Wkc[r][e] = ldFlag(kv_w, (size_t)c * 768 + hd * 48 + e, f);
        }
        __syncthreads();
        for (int r = 0; r < 32; r++) {
#pragma unroll
            for (int j = 0; j < 9; j++) acc[j] += Wkc[r][dj[j]] * Pc[r][ej[j]];
        }
        __syncthreads();
    }
#pragma unroll
    for (int j = 0; j < 9; j++) Ss[dj[j]][ej[j]] = acc[j] * SCALE;
    __syncthreads();
    if (t < 48) {
        float m = -1e30f;
#pragma unroll
        for (int e = 0; e < 48; e++) m = fmaxf(m, Ss[t][e]);
        float ex[48];
        float sum = 0;
#pragma unroll
        for (int e = 0; e < 48; e++) {
            ex[e] = expf(Ss[t][e] - m);
            sum += ex[e];
        }
        float inv = 1.0f / sum;
#pragma unroll
        for (int e = 0; e < 48; e++)
            attn[((size_t)b * NH + hd) * 2304 + t * 48 + e] = ex[e] * inv;
    }
}

// ------- Wtilde[b][c][h*48+d] = sum_e Wq[c, h*48+e] * attn[b,h,d,e]. grid (6, NH, Bq). -------
__global__ __launch_bounds__(256) void wtilde_k(const void* __restrict__ q_w,
                                                const float* __restrict__ attn,
                                                bf16* __restrict__ Wt_,
                                                const int* __restrict__ flagp) {
    int f = *flagp;
    int c0 = blockIdx.x * 64;
    int hd = blockIdx.y;
    int b = blockIdx.z;
    int t = threadIdx.x;
    __shared__ float at[48][48];
    __shared__ float wq[64][48];
    const float* ab = attn + ((size_t)b * NH + hd) * 2304;
    for (int o = t; o < 2304; o += 256) at[o / 48][o % 48] = ab[o];
    for (int o = t; o < 3072; o += 256) {
        int cc = o / 48, e = o % 48;
        wq[cc][e] = ldFlag(q_w, (size_t)(c0 + cc) * Cc + hd * 48 + e, f);
    }
    __syncthreads();
    bf16* outb = Wt_ + (size_t)b * Cc * Cc;
    for (int o = t; o < 3072; o += 256) {
        int cc = o / 48, d = o % 48;
        float s = 0;
#pragma unroll
        for (int e = 0; e < 48; e++) s += wq[cc][e] * at[d][e];
        outb[(size_t)(c0 + cc) * Cc + hd * 48 + d] = __float2bfloat16(s);
    }
}

extern "C" void kernel_launch(void* const* d_in, const int* in_sizes, int n_in,
                              void* d_out, int out_size, void* d_ws, size_t ws_size,
                              hipStream_t stream) {
    (void)in_sizes; (void)n_in; (void)out_size;
    const void* x = d_in[0];
    const void* srcp = d_in[1];
    const void* cpe0_w = d_in[4];
    const void* cpe0_b = d_in[5];
    const void* cpe1_w = d_in[6];
    const void* cpe1_b = d_in[7];
    const void* n1g = d_in[8];
    const void* n1b = d_in[9];
    const void* q_w = d_in[10];
    const void* kv_w = d_in[11];
    const void* proj_w = d_in[12];
    const void* proj_b = d_in[13];
    const void* n2g = d_in[14];
    const void* n2b = d_in[15];
    const void* fc1_w = d_in[16];
    const void* fc1_b = d_in[17];
    const void* fc2_w = d_in[18];
    const void* fc2_b = d_in[19];
    char* ws = (char*)d_ws;

    // ---- workspace layout ----
    const size_t CcCc = (size_t)Cc * Cc;
    const size_t NnCc = (size_t)Nn * Cc;
    const size_t SLOT = (size_t)Mrows * Cc * sizeof(bf16);  // 25,165,824
    int* flag = (int*)ws;
    bf16* s0 = (bf16*)(ws + 64);            // lnS -> x2 -> h1c
    bf16* s1 = (bf16*)(ws + 64 + SLOT);     // Gp (18.9MB fp32) -> WeffT (bf16) -> x3
    float* Gp = (float*)s1;
    u16t* WeffT = (u16t*)s1;                // [Bq][384(c_out)][384(c_in)] bf16
    bf16* x3 = s1;
    float* P = (float*)(ws + 64 + 2 * SLOT);        // 4,718,592 [Bq][384x384] fp32
    bf16* Wt_ = (bf16*)P;                           // alias (P dead after attn_s)
    u16t* projT = (u16t*)((char*)P + 2359296);      // [c_out][e] bf16, after attn_s
    u16t* fc1T = (u16t*)P;                          // [1536][384] bf16, after Weff gemm
    u16t* fc2T = (u16t*)((char*)P + 1179648);       // [384][1536] bf16
    float* attnB = (float*)(ws + 64 + 2 * SLOT + 4718592);  // 589,824
    float* mu2 = (float*)(ws + 64 + 2 * SLOT + 4718592 + 589824);
    float* rs2 = mu2 + Mrows;
    u16t* gB = (u16t*)(rs2 + Mrows);  // 384 bf16 LN2 gamma
    u16t* bB = gB + 384;              // 384 bf16 LN2 beta
    bf16* lnS = s0;
    bf16* x2 = s0;
    u16t* h1c = (u16t*)s0;  // CR=8192 -> 25.17 MB, exact fit
    const size_t NEED = (size_t)((char*)(bB + 384) - ws);
    if (ws_size < NEED) return;

    bf16* lnX = (bf16*)d_out;  // d_out as bf16 scratch (dead before final writes)

    probe_k<<<1, 256, 0, stream>>>(x, flag);
    prep_k<<<1, 384, 0, stream>>>(n2g, n2b, gB, bB, flag);

    // 1. lnX = LN1(cpe0(x)) fused
    dwconv_ln<2, 0><<<dim3(Ww / 8, Hh, Bq), 384, 0, stream>>>(
        x, cpe0_w, cpe0_b, lnX, n1g, n1b, nullptr, nullptr, flag);

    // 2. lnS = LN1(cpe0(source)) fused -> MFMA gram partials (plain bf16)
    dwconv_ln<2, 0><<<dim3(Ww / 8, Hh, Bq), 384, 0, stream>>>(
        srcp, cpe0_w, cpe0_b, lnS, n1g, n1b, nullptr, nullptr, flag);
    gram_mfma<<<dim3(9, NS, Bq), 256, 0, stream>>>((const u16t*)lnS, Gp);

    // 3. P_b = (sum_s Gp[b,s]) @ Wv   (fp32 scalar, AR=4; Wv = kv_w cols 384..767)
    gemm_k<0, 2, 2, false, false, 0, NS><<<dim3(6, 6, Bq), 256, 0, stream>>>(
        Gp, (size_t)NS * CcCc, kv_w, 0, 768, 384, nullptr, nullptr, 0,
        nullptr, nullptr, 0, nullptr, nullptr, P, CcCc, 0, Cc, Cc, Cc, flag);

    // 4. attn path + fold into WeffT[c_out][c_in] = (Wt @ proj_w)^T via swapped MFMA gemm
    attn_s_k<<<dim3(NH, Bq), 256, 0, stream>>>(P, kv_w, attnB, flag);
    wtilde_k<<<dim3(6, NH, Bq), 256, 0, stream>>>(q_w, attnB, Wt_, flag);
    transpose_k<<<dim3(6, 6), 256, 0, stream>>>(proj_w, projT, Cc, Cc, flag);
    gemm_mfma<0, 1, false, 0><<<dim3(3, 3, Bq), 256, 0, stream>>>(
        projT, 0, (const u16t*)Wt_, CcCc, nullptr, nullptr, 0,
        nullptr, nullptr, 0, nullptr, nullptr, WeffT, CcCc, 0, Cc, Cc, flag);

    // MLP weight transposes (P region free of Wt_ after Weff gemm; stream-ordered)
    transpose_k<<<dim3(24, 6), 256, 0, stream>>>(fc1_w, fc1T, Cc, CH, flag);
    transpose_k<<<dim3(6, 24), 256, 0, stream>>>(fc2_w, fc2T, CH, Cc, flag);

    // 5. x2 = lnX + lnX @ Weff_b + proj_b   (plain MFMA, RES=2 adds A element)
    gemm_mfma<0, 1, false, 2><<<dim3(32, 3, Bq), 256, 0, stream>>>(
        (const u16t*)lnX, NnCc, WeffT, CcCc, proj_b, nullptr, 0,
        nullptr, nullptr, 0, nullptr, nullptr, x2, NnCc, 0, Cc, Cc, flag);

    // 6. x3 = cpe1(x2) raw + LN2 stats (fused)
    dwconv_ln<1, 1><<<dim3(Ww / 8, Hh, Bq), 384, 0, stream>>>(
        x2, cpe1_w, cpe1_b, x3, nullptr, nullptr, mu2, rs2, flag);

    // 7. MLP in 8192-row chunks: out = x3 + gelu(LN2(x3)@fc1+b1)@fc2+b2
    constexpr int CR = 8192;
    for (int ch = 0; ch < Mrows / CR; ch++) {
        size_t roff = (size_t)ch * CR;
        gemm_mfma<1, 1, true, 0><<<dim3(CR / 128, CH / 128, 1), 256, 0, stream>>>(
            (const u16t*)x3 + roff * Cc, 0, fc1T, 0, fc1_b, nullptr, 0,
            mu2 + roff, rs2 + roff, 0, gB, bB, h1c, 0, 0, Cc, CH, flag);
        gemm_mfma<0, 0, false, 1><<<dim3(CR / 128, Cc / 128, 1), 256, 0, stream>>>(
            h1c, 0, fc2T, 0, fc2_b, (const u16t*)x3 + roff * Cc, 0,
            nullptr, nullptr, 0, nullptr, nullptr, d_out, 0, roff, CH, Cc, flag);
    }
}